// Round 15
// baseline (132.715 us; speedup 1.0000x reference)
//
#include <hip/hip_runtime.h>

#define S_TOT 2048
#define BATCH 128
#define FEAT  256
#define CHUNK 128   // k-rows per pipeline stage (8 barriers total)
#define ROWH  136   // 128 halves + 8 pad; 272 B stride (16B-aligned rows)
#define GROWS 16    // rows per gather block

typedef _Float16 f16x8 __attribute__((ext_vector_type(8)));
typedef _Float16 f16x2 __attribute__((ext_vector_type(2)));
typedef float f32x4 __attribute__((ext_vector_type(4)));

// Fused stats + Gram via MFMA, row-split 2 blocks/batch, XCD-pair swizzle.
// R15: CHUNK=128 (halves barrier count; 136 KB LDS, still 1 block/CU) and
// gfx950-native mfma_f32_16x16x32_f16 (K=32: halves MFMA + ds_read counts).
// Gram correctness is k-layout-robust: A=B=T means any internal k-permutation
// applies to both operands identically, so G = sum_k T[m,k]T[n,k] exactly.
// Correlation is affine-invariant: stage RAW f16, MFMA the Gram, per-feature
// sum/sumsq of the SAME f16-rounded values in fp32, then threshold
// (G - n*mi*mj) / ((n-1)*si*sj) > 0.999.
// Ref's +1e-6 std shift scales cov by ~2e-6: irrelevant vs 1e-3 margins.
// sigma=0 features: is_=0 -> cv=0 -> never selected (matches ref).
__global__ __launch_bounds__(1024) void k_cov(
        const float* __restrict__ x, const int* __restrict__ sep,
        int* __restrict__ colsum_part) {
    const int d = blockIdx.x;               // 0..255
    const int b = (d & 7) + 8 * (d >> 4);   // XCD-pair remap (bijective)
    const int half = (d >> 3) & 1;          // halves of b are 8 slots apart
    const int n = sep[0];
    const int t = threadIdx.x;
    const int l = t & 63;
    const int w = t >> 6;               // 0..15; wave tile = 32 rows x 64 cols
    const int wm = w >> 2, wn = w & 3;
    const int l15 = l & 15, lg = l >> 4;

    __shared__ _Float16 T[2][FEAT][ROWH];   // 136 KB
    __shared__ float ms[FEAT], is_[FEAT];
    __shared__ int scount[FEAT];
    float* redf = (float*)&T[0][0][0];  // post-loop overlay: [2][16][FEAT]

    // staging role: thread covers features f4..f4+3, chunk-rows
    // 2w+{0,1}+32g for g=0..3 (w = wave id)
    const int fg = t & 63;
    const int f4 = fg * 4;

    f32x4 acc[2][4];
#pragma unroll
    for (int r = 0; r < 2; ++r)
#pragma unroll
        for (int c = 0; c < 4; ++c)
            acc[r][c] = (f32x4){0.f, 0.f, 0.f, 0.f};

    float psum[4] = {0.f, 0.f, 0.f, 0.f};
    float psq[4] = {0.f, 0.f, 0.f, 0.f};
    f32x4 st[8];   // all indices compile-time after unroll

    const size_t colbase = (size_t)b * FEAT + f4;
    const int NC = (n + CHUNK - 1) / CHUNK;

    if (t < FEAT) scount[t] = 0;

#define LOADC(c)                                                            \
    {                                                                       \
        const f32x4 z = (f32x4){0.f, 0.f, 0.f, 0.f};                        \
        _Pragma("unroll")                                                   \
        for (int g = 0; g < 4; ++g) {                                       \
            const int r0 = (c) * CHUNK + 2 * w + 32 * g;                    \
            st[2 * g] = (r0 < n) ? *(const f32x4*)&x[(size_t)r0 * (BATCH * FEAT) + colbase] : z; \
            st[2 * g + 1] = (r0 + 1 < n) ? *(const f32x4*)&x[(size_t)(r0 + 1) * (BATCH * FEAT) + colbase] : z; \
        }                                                                   \
    }

#define CVTC(buf)                                                           \
    {                                                                       \
        _Pragma("unroll")                                                   \
        for (int g = 0; g < 4; ++g) {                                       \
            _Pragma("unroll")                                               \
            for (int j = 0; j < 4; ++j) {                                   \
                _Float16 h0 = (_Float16)st[2 * g][j];                       \
                _Float16 h1 = (_Float16)st[2 * g + 1][j];                   \
                float r0 = (float)h0, r1 = (float)h1;                       \
                psum[j] += r0 + r1;                                         \
                psq[j] = fmaf(r0, r0, psq[j]);                              \
                psq[j] = fmaf(r1, r1, psq[j]);                              \
                *(f16x2*)&T[buf][f4 + j][2 * w + 32 * g] = (f16x2){h0, h1}; \
            }                                                               \
        }                                                                   \
    }

#define MFMAC(buf)                                                          \
    {                                                                       \
        _Pragma("unroll")                                                   \
        for (int ks = 0; ks < 4; ++ks) {                                    \
            const int kloc = ks * 32 + 8 * lg;                              \
            f16x8 a[2], bb[4];                                              \
            _Pragma("unroll")                                               \
            for (int r = 0; r < 2; ++r)                                     \
                a[r] = *(const f16x8*)&T[buf][half * 128 + wm * 32 + r * 16 + l15][kloc]; \
            _Pragma("unroll")                                               \
            for (int c2 = 0; c2 < 4; ++c2)                                  \
                bb[c2] = *(const f16x8*)&T[buf][wn * 64 + c2 * 16 + l15][kloc]; \
            _Pragma("unroll")                                               \
            for (int r = 0; r < 2; ++r)                                     \
                _Pragma("unroll")                                           \
                for (int c2 = 0; c2 < 4; ++c2)                              \
                    acc[r][c2] = __builtin_amdgcn_mfma_f32_16x16x32_f16(    \
                        a[r], bb[c2], acc[r][c2], 0, 0, 0);                 \
        }                                                                   \
    }

    // prologue: chunk 0 -> regs -> buf 0
    LOADC(0);
    CVTC(0);
    __syncthreads();

    for (int c = 0; c < NC; ++c) {
        const int cur = c & 1;
        const bool more = (c + 1 < NC);
        if (more) LOADC(c + 1);
        MFMAC(cur);                 // prefetch loads drain under this
        if (more) CVTC(cur ^ 1);
        __syncthreads();
    }

    // fold per-feature partials: wave w holds partials for features f4..f4+3
#pragma unroll
    for (int j = 0; j < 4; ++j) {
        redf[w * FEAT + f4 + j] = psum[j];
        redf[16 * FEAT + w * FEAT + f4 + j] = psq[j];
    }
    __syncthreads();
    if (t < FEAT) {
        float s = 0.f, q = 0.f;
#pragma unroll
        for (int k = 0; k < 16; ++k) {
            s += redf[k * FEAT + t];
            q += redf[16 * FEAT + k * FEAT + t];
        }
        float m = s / (float)n;
        float var = (q - (float)n * m * m) / (float)(n - 1);
        ms[t] = m;
        is_[t] = (var > 0.f) ? rsqrtf(var) : 0.f;
    }
    __syncthreads();

    const float fn = (float)n;
    const float inv_nm1 = 1.f / (float)(n - 1);
#pragma unroll
    for (int c = 0; c < 4; ++c) {
        const int gj = wn * 64 + c * 16 + l15;
        const float mj = ms[gj], ij = is_[gj];
        int cnt = 0;
#pragma unroll
        for (int r = 0; r < 2; ++r) {
            const int gib = half * 128 + wm * 32 + r * 16 + 4 * lg;
#pragma unroll
            for (int q = 0; q < 4; ++q) {
                const int gi = gib + q;
                float cv = (acc[r][c][q] - fn * ms[gi] * mj) * inv_nm1 * is_[gi] * ij;
                if (gi <= gj && cv > 0.999f) cnt++;
            }
        }
        if (cnt) atomicAdd(&scount[gj], cnt);
    }
    __syncthreads();
    if (t < FEAT) colsum_part[(half * BATCH + b) * FEAT + t] = scount[t];
}

// gather with FUSED select: each block recomputes the stable ballot-order
// from colsum_part (2 KB L2-hit read + ~50 instrs). counts==FEAT =>
// identity permutation, no mask => pure NT float4 copy (no LDS). Grid
// b-fastest: consecutive blocks stream contiguous HBM.
__global__ __launch_bounds__(256) void k_gather(
        const float* __restrict__ x, const int* __restrict__ colsum_part,
        float* __restrict__ out) {
    const int b = blockIdx.x;
    const int s0 = blockIdx.y * GROWS;
    const int t = threadIdx.x;          // 0..255 == feature j

    __shared__ float T[GROWS][FEAT];
    __shared__ int ord_s[FEAT];
    __shared__ int wsum[4];

    // inline stable select (ballot prefix)
    const int cs = colsum_part[b * FEAT + t] +
                   colsum_part[(BATCH + b) * FEAT + t];
    const int sel = (cs == 1) ? 1 : 0;
    unsigned long long mask = __ballot(sel);
    const int lane = t & 63;
    const int wid = t >> 6;
    int pre = __popcll(mask & ((1ull << lane) - 1ull));
    if (lane == 0) wsum[wid] = __popcll(mask);
    __syncthreads();
    int woff = 0;
#pragma unroll
    for (int w = 0; w < 4; ++w) woff += (w < wid) ? wsum[w] : 0;
    const int total = wsum[0] + wsum[1] + wsum[2] + wsum[3];
    if (sel) {
        ord_s[woff + pre] = t;
    } else {
        ord_s[total + (t - woff - pre)] = t;
    }

    const size_t bbase = (size_t)b * FEAT;

    if (total == FEAT) {
        // identity permutation, no masking: straight NT copy
#pragma unroll
        for (int i = 0; i < (GROWS * FEAT) / (256 * 4); ++i) {
            const int idx = i * 256 + t;
            const int row = idx >> 6;
            const int f4 = (idx & 63) * 4;
            const size_t off = (size_t)(s0 + row) * (BATCH * FEAT) + bbase + f4;
            f32x4 v = *(const f32x4*)&x[off];
            __builtin_nontemporal_store(v, (f32x4*)&out[off]);
        }
        return;
    }

    __syncthreads();   // ord_s ready (slow path only)

#pragma unroll
    for (int i = 0; i < (GROWS * FEAT) / (256 * 4); ++i) {  // 4 float4/thread
        const int idx = i * 256 + t;
        const int row = idx >> 6;
        const int f4 = (idx & 63) * 4;
        float4 v = *(const float4*)&x[(size_t)(s0 + row) * (BATCH * FEAT) + bbase + f4];
        *(float4*)&T[row][f4] = v;
    }
    __syncthreads();

    const int c4 = (t & 63) * 4;
    const int tr = t >> 6;               // 0..3
    const int o0 = ord_s[c4 + 0], o1 = ord_s[c4 + 1];
    const int o2 = ord_s[c4 + 2], o3 = ord_s[c4 + 3];
#pragma unroll
    for (int r = tr; r < GROWS; r += 4) {
        f32x4 v;
        v.x = (c4 + 0 < total) ? T[r][o0] : 0.f;
        v.y = (c4 + 1 < total) ? T[r][o1] : 0.f;
        v.z = (c4 + 2 < total) ? T[r][o2] : 0.f;
        v.w = (c4 + 3 < total) ? T[r][o3] : 0.f;
        __builtin_nontemporal_store(v,
            (f32x4*)&out[(size_t)(s0 + r) * (BATCH * FEAT) + bbase + c4]);
    }
}

extern "C" void kernel_launch(void* const* d_in, const int* in_sizes, int n_in,
                              void* d_out, int out_size, void* d_ws, size_t ws_size,
                              hipStream_t stream) {
    const float* x = (const float*)d_in[0];
    const int* sep = (const int*)d_in[1];
    float* out = (float*)d_out;

    int* colsum_part = (int*)d_ws;                     // [2][BATCH][FEAT]

    k_cov<<<dim3(2 * BATCH), dim3(1024), 0, stream>>>(x, sep, colsum_part);

    k_gather<<<dim3(BATCH, S_TOT / GROWS), dim3(256), 0, stream>>>(x, colsum_part, out);
}

// Round 17
// 118.981 us; speedup vs baseline: 1.1154x; 1.1154x over previous
//
#include <hip/hip_runtime.h>

#define S_TOT 2048
#define BATCH 128
#define FEAT  256
#define CHUNK 64    // k-rows per pipeline stage (2 MB/XCD -> L2 dedup works)
#define ROWH  68    // 64 halves + 4 pad; 136 B row stride (8B-aligned rows)
#define GROWS 32    // rows per gather block

typedef _Float16 f16x4 __attribute__((ext_vector_type(4)));
typedef _Float16 f16x8 __attribute__((ext_vector_type(8)));
typedef _Float16 f16x2 __attribute__((ext_vector_type(2)));
typedef float f32x4 __attribute__((ext_vector_type(4)));

// Fused stats + Gram via MFMA, row-split 2 blocks/batch, XCD-pair swizzle.
// CHUNK=64 (2 MB/XCD working set -> L2 pair-dedup holds; CHUNK=128 = 4 MB
// regressed in R15). K=32 MFMA (mfma_f32_16x16x32_f16, silicon-verified
// R15): fragment = two 8B-aligned b64 reads, half the MFMA issue slots.
// Correlation is affine-invariant: stage RAW f16, MFMA the Gram, per-feature
// sum/sumsq of the SAME f16-rounded values in fp32, then threshold
// (G - n*mi*mj) / ((n-1)*si*sj) > 0.999. Gram is k-permutation-robust
// (A=B=T). Ref's +1e-6 std shift ~2e-6 scale: irrelevant vs 1e-3 margins.
// sigma=0 features: is_=0 -> cv=0 -> never selected (matches ref).
__global__ __launch_bounds__(1024) void k_cov(
        const float* __restrict__ x, const int* __restrict__ sep,
        int* __restrict__ colsum_part) {
    const int d = blockIdx.x;               // 0..255
    const int b = (d & 7) + 8 * (d >> 4);   // XCD-pair remap (bijective)
    const int half = (d >> 3) & 1;          // halves of b are 8 slots apart
    const int n = sep[0];
    const int t = threadIdx.x;
    const int l = t & 63;
    const int w = t >> 6;               // 0..15; wave tile = 32 rows x 64 cols
    const int wm = w >> 2, wn = w & 3;
    const int l15 = l & 15, lg = l >> 4;

    __shared__ _Float16 T[2][FEAT][ROWH];
    __shared__ float ms[FEAT], is_[FEAT];
    __shared__ int scount[FEAT];
    float* redf = (float*)&T[0][0][0];  // post-loop overlay: [2][16][FEAT]

    // staging role: thread covers features f4..f4+3, chunk-rows
    // {2w, 2w+1, 2w+32, 2w+33} (w = wave id)
    const int fg = t & 63;
    const int f4 = fg * 4;

    f32x4 acc[2][4];
#pragma unroll
    for (int r = 0; r < 2; ++r)
#pragma unroll
        for (int c = 0; c < 4; ++c)
            acc[r][c] = (f32x4){0.f, 0.f, 0.f, 0.f};

    float psum[4] = {0.f, 0.f, 0.f, 0.f};
    float psq[4] = {0.f, 0.f, 0.f, 0.f};
    f32x4 st[4];

    const size_t colbase = (size_t)b * FEAT + f4;
    const int NC = (n + CHUNK - 1) / CHUNK;

    if (t < FEAT) scount[t] = 0;

#define LOADC(c)                                                            \
    {                                                                       \
        const int r0 = (c) * CHUNK + 2 * w;                                 \
        const f32x4 z = (f32x4){0.f, 0.f, 0.f, 0.f};                        \
        st[0] = (r0 + 0 < n) ? *(const f32x4*)&x[(size_t)(r0 + 0) * (BATCH * FEAT) + colbase] : z; \
        st[1] = (r0 + 1 < n) ? *(const f32x4*)&x[(size_t)(r0 + 1) * (BATCH * FEAT) + colbase] : z; \
        st[2] = (r0 + 32 < n) ? *(const f32x4*)&x[(size_t)(r0 + 32) * (BATCH * FEAT) + colbase] : z; \
        st[3] = (r0 + 33 < n) ? *(const f32x4*)&x[(size_t)(r0 + 33) * (BATCH * FEAT) + colbase] : z; \
    }

#define CVTC(buf)                                                           \
    {                                                                       \
        _Pragma("unroll")                                                   \
        for (int j = 0; j < 4; ++j) {                                       \
            _Float16 h0 = (_Float16)st[0][j], h1 = (_Float16)st[1][j];      \
            _Float16 h2 = (_Float16)st[2][j], h3 = (_Float16)st[3][j];      \
            float r0 = (float)h0, r1 = (float)h1, r2 = (float)h2, r3 = (float)h3; \
            psum[j] += (r0 + r1) + (r2 + r3);                               \
            psq[j] = fmaf(r0, r0, psq[j]);                                  \
            psq[j] = fmaf(r1, r1, psq[j]);                                  \
            psq[j] = fmaf(r2, r2, psq[j]);                                  \
            psq[j] = fmaf(r3, r3, psq[j]);                                  \
            *(f16x2*)&T[buf][f4 + j][2 * w] = (f16x2){h0, h1};              \
            *(f16x2*)&T[buf][f4 + j][2 * w + 32] = (f16x2){h2, h3};         \
        }                                                                   \
    }

// K=32 MFMA; frag = two 8B-aligned f16x4 (b64) reads at kloc, kloc+4.
#define MFMAC(buf)                                                          \
    {                                                                       \
        _Pragma("unroll")                                                   \
        for (int ks = 0; ks < 2; ++ks) {                                    \
            const int kloc = ks * 32 + 8 * lg;                              \
            f16x8 a[2], bb[4];                                              \
            _Pragma("unroll")                                               \
            for (int r = 0; r < 2; ++r) {                                   \
                const _Float16* rp = &T[buf][half * 128 + wm * 32 + r * 16 + l15][kloc]; \
                f16x4 lo = *(const f16x4*)rp, hi = *(const f16x4*)(rp + 4); \
                a[r] = (f16x8){lo[0], lo[1], lo[2], lo[3], hi[0], hi[1], hi[2], hi[3]}; \
            }                                                               \
            _Pragma("unroll")                                               \
            for (int c2 = 0; c2 < 4; ++c2) {                                \
                const _Float16* rp = &T[buf][wn * 64 + c2 * 16 + l15][kloc]; \
                f16x4 lo = *(const f16x4*)rp, hi = *(const f16x4*)(rp + 4); \
                bb[c2] = (f16x8){lo[0], lo[1], lo[2], lo[3], hi[0], hi[1], hi[2], hi[3]}; \
            }                                                               \
            _Pragma("unroll")                                               \
            for (int r = 0; r < 2; ++r)                                     \
                _Pragma("unroll")                                           \
                for (int c2 = 0; c2 < 4; ++c2)                              \
                    acc[r][c2] = __builtin_amdgcn_mfma_f32_16x16x32_f16(    \
                        a[r], bb[c2], acc[r][c2], 0, 0, 0);                 \
        }                                                                   \
    }

    // prologue: chunk 0 -> regs -> buf 0
    LOADC(0);
    CVTC(0);
    __syncthreads();

    for (int c = 0; c < NC; ++c) {
        const int cur = c & 1;
        const bool more = (c + 1 < NC);
        if (more) LOADC(c + 1);
        MFMAC(cur);                 // prefetch loads drain under this
        if (more) CVTC(cur ^ 1);
        __syncthreads();
    }

    // fold per-feature partials: wave w holds partials for features f4..f4+3
#pragma unroll
    for (int j = 0; j < 4; ++j) {
        redf[w * FEAT + f4 + j] = psum[j];
        redf[16 * FEAT + w * FEAT + f4 + j] = psq[j];
    }
    __syncthreads();
    if (t < FEAT) {
        float s = 0.f, q = 0.f;
#pragma unroll
        for (int k = 0; k < 16; ++k) {
            s += redf[k * FEAT + t];
            q += redf[16 * FEAT + k * FEAT + t];
        }
        float m = s / (float)n;
        float var = (q - (float)n * m * m) / (float)(n - 1);
        ms[t] = m;
        is_[t] = (var > 0.f) ? rsqrtf(var) : 0.f;
    }
    __syncthreads();

    const float fn = (float)n;
    const float inv_nm1 = 1.f / (float)(n - 1);
#pragma unroll
    for (int c = 0; c < 4; ++c) {
        const int gj = wn * 64 + c * 16 + l15;
        const float mj = ms[gj], ij = is_[gj];
        int cnt = 0;
#pragma unroll
        for (int r = 0; r < 2; ++r) {
            const int gib = half * 128 + wm * 32 + r * 16 + 4 * lg;
#pragma unroll
            for (int q = 0; q < 4; ++q) {
                const int gi = gib + q;
                float cv = (acc[r][c][q] - fn * ms[gi] * mj) * inv_nm1 * is_[gi] * ij;
                if (gi <= gj && cv > 0.999f) cnt++;
            }
        }
        if (cnt) atomicAdd(&scount[gj], cnt);
    }
    __syncthreads();
    if (t < FEAT) colsum_part[(half * BATCH + b) * FEAT + t] = scount[t];
}

// gather with FUSED select (512 threads, GROWS=32). All barriers at top
// level, uniform across the block — R16's barrier-inside-divergent-branch
// raced waves 4-7 past the select phase. Phase1: t<256 ballot + wsum;
// sync; Phase2: t<256 ord_s/total_s; sync; then all 512 threads gather.
// counts==FEAT => identity permutation => pure NT float4 copy (no LDS).
// Grid b-fastest: consecutive blocks stream contiguous HBM.
__global__ __launch_bounds__(512) void k_gather(
        const float* __restrict__ x, const int* __restrict__ colsum_part,
        float* __restrict__ out) {
    const int b = blockIdx.x;
    const int s0 = blockIdx.y * GROWS;
    const int t = threadIdx.x;          // 0..511

    __shared__ float T[GROWS][FEAT];
    __shared__ int ord_s[FEAT];
    __shared__ int wsum[4];
    __shared__ int total_s;

    int sel = 0, pre = 0, wid = 0;
    if (t < FEAT) {                     // phase 1: ballot + per-wave counts
        const int cs = colsum_part[b * FEAT + t] +
                       colsum_part[(BATCH + b) * FEAT + t];
        sel = (cs == 1) ? 1 : 0;
        unsigned long long mask = __ballot(sel);
        const int lane = t & 63;
        wid = t >> 6;
        pre = __popcll(mask & ((1ull << lane) - 1ull));
        if (lane == 0) wsum[wid] = __popcll(mask);
    }
    __syncthreads();                    // uniform barrier #1

    if (t < FEAT) {                     // phase 2: scatter order
        int woff = 0;
#pragma unroll
        for (int w = 0; w < 4; ++w) woff += (w < wid) ? wsum[w] : 0;
        const int total = wsum[0] + wsum[1] + wsum[2] + wsum[3];
        if (sel) {
            ord_s[woff + pre] = t;
        } else {
            ord_s[total + (t - woff - pre)] = t;
        }
        if (t == 0) total_s = total;
    }
    __syncthreads();                    // uniform barrier #2

    const int total = total_s;
    const size_t bbase = (size_t)b * FEAT;

    if (total == FEAT) {
        // identity permutation, no masking: straight NT copy
#pragma unroll
        for (int i = 0; i < (GROWS * FEAT) / (512 * 4); ++i) {
            const int idx = i * 512 + t;
            const int row = idx >> 6;
            const int f4 = (idx & 63) * 4;
            const size_t off = (size_t)(s0 + row) * (BATCH * FEAT) + bbase + f4;
            f32x4 v = *(const f32x4*)&x[off];
            __builtin_nontemporal_store(v, (f32x4*)&out[off]);
        }
        return;
    }

#pragma unroll
    for (int i = 0; i < (GROWS * FEAT) / (512 * 4); ++i) {  // 4 float4/thread
        const int idx = i * 512 + t;
        const int row = idx >> 6;
        const int f4 = (idx & 63) * 4;
        float4 v = *(const float4*)&x[(size_t)(s0 + row) * (BATCH * FEAT) + bbase + f4];
        *(float4*)&T[row][f4] = v;
    }
    __syncthreads();

    const int c4 = (t & 63) * 4;
    const int tr = t >> 6;               // 0..7
    const int o0 = ord_s[c4 + 0], o1 = ord_s[c4 + 1];
    const int o2 = ord_s[c4 + 2], o3 = ord_s[c4 + 3];
#pragma unroll
    for (int r = tr; r < GROWS; r += 8) {
        f32x4 v;
        v.x = (c4 + 0 < total) ? T[r][o0] : 0.f;
        v.y = (c4 + 1 < total) ? T[r][o1] : 0.f;
        v.z = (c4 + 2 < total) ? T[r][o2] : 0.f;
        v.w = (c4 + 3 < total) ? T[r][o3] : 0.f;
        __builtin_nontemporal_store(v,
            (f32x4*)&out[(size_t)(s0 + r) * (BATCH * FEAT) + bbase + c4]);
    }
}

extern "C" void kernel_launch(void* const* d_in, const int* in_sizes, int n_in,
                              void* d_out, int out_size, void* d_ws, size_t ws_size,
                              hipStream_t stream) {
    const float* x = (const float*)d_in[0];
    const int* sep = (const int*)d_in[1];
    float* out = (float*)d_out;

    int* colsum_part = (int*)d_ws;                     // [2][BATCH][FEAT]

    k_cov<<<dim3(2 * BATCH), dim3(1024), 0, stream>>>(x, sep, colsum_part);

    k_gather<<<dim3(BATCH, S_TOT / GROWS), dim3(512), 0, stream>>>(x, colsum_part, out);
}